// Round 12
// baseline (4378.093 us; speedup 1.0000x reference)
//
#include <hip/hip_runtime.h>

typedef unsigned short u16;
typedef __attribute__((ext_vector_type(8))) short short8;
typedef __attribute__((ext_vector_type(4))) float f32x4;
typedef __attribute__((ext_vector_type(4))) unsigned short us4;

__device__ __forceinline__ u16 f2bf(float f) {
    unsigned u = __float_as_uint(f);
    u += 0x7fffu + ((u >> 16) & 1u);   // round-to-nearest-even
    return (u16)(u >> 16);
}
__device__ __forceinline__ float bf2f(u16 h) {
    return __uint_as_float(((unsigned)h) << 16);
}

// ---------------- X f32 -> bf16 (4 elems/thread) ----------------
__global__ __launch_bounds__(256) void k_cvt(const float* __restrict__ in,
                                             u16* __restrict__ out, long n) {
    long i = ((long)blockIdx.x * 256 + threadIdx.x) * 4;
    if (i >= n) return;
    float4 v = *(const float4*)(in + i);
    us4 o;
    o.x = f2bf(v.x); o.y = f2bf(v.y); o.z = f2bf(v.z); o.w = f2bf(v.w);
    *(us4*)(out + i) = o;
}

// ---------------- W (K,N) f32 -> Wt (N,K) bf16, block-tri mask ----------------
__global__ __launch_bounds__(256) void k_transpose(const float* __restrict__ W,
                                                   u16* __restrict__ Wt,
                                                   int K, int N, int mask) {
    __shared__ float tile[32][33];
    const int n0 = blockIdx.x * 32, k0 = blockIdx.y * 32;
    const int tx = threadIdx.x, ty = threadIdx.y;
    if (mask && ((k0 >> 6) > (n0 >> 6))) {
        if (k0 >= ((n0 >> 8) + 1) * 256) return;   // never read by varK GEMM
#pragma unroll
        for (int j = 0; j < 32; j += 8)
            Wt[(size_t)(n0 + ty + j) * K + (k0 + tx)] = 0;
        return;
    }
#pragma unroll
    for (int j = 0; j < 32; j += 8)
        tile[ty + j][tx] = W[(size_t)(k0 + ty + j) * N + (n0 + tx)];
    __syncthreads();
#pragma unroll
    for (int j = 0; j < 32; j += 8)
        Wt[(size_t)(n0 + ty + j) * K + (k0 + tx)] = f2bf(tile[tx][ty + j]);
}

// ---------------- extract W3[:, N-1] ----------------
__global__ __launch_bounds__(256) void k_extract(const float* __restrict__ W3,
                                                 float* __restrict__ col, int N) {
    int k = blockIdx.x * 256 + threadIdx.x;
    col[k] = W3[(size_t)k * N + (N - 1)];
}

// ---------------- bf16 GEMM: C = relu(A @ Bt^T + bias) -> bf16 ----------------
// R12: TLP-overlap structure.  256x256 tile, BK=32, 512 threads (8 waves 2x4),
// DOUBLE-buffered LDS = 64 KiB -> TWO co-resident blocks per CU (16 waves/CU).
// While one block sits in its barrier/lgkm drain, the other issues MFMA
// (m114-verified co-issue).  Per tile: [12 ds_read(T) | 32 MFMA | SB | BAR1
// (all reads retired) | stage(T+2)->buf(T&1) (WAR-safe after BAR1) | vmcnt(4/0)
// (T+1 landed, counted per-wave, published by) | BAR2].  sched_barrier pins the
// MFMA cluster (and its lgkm waits) before BAR1 (rule #18).  XOR-swizzle
// slot^=(row>>1)&3 on both stage-source and ds_read (0 conflicts, R9-proven).
#define BM 256
#define BN 256
#define BK 32
#define BUFE 16384                     // elems per buffer: A 8192 | B 8192
#define GLDS(src, dst)                                                          \
    __builtin_amdgcn_global_load_lds(                                           \
        (const __attribute__((address_space(1))) void*)(src),                   \
        (__attribute__((address_space(3))) void*)(dst), 16, 0, 0)

__global__ __launch_bounds__(512, 4) void k_gemm(const u16* __restrict__ A,
                                                 const u16* __restrict__ Bt,
                                                 const float* __restrict__ bias,
                                                 u16* __restrict__ C,
                                                 int M, int N, int K, int varK) {
    __shared__ __align__(16) u16 lds[2 * BUFE];   // 64 KiB -> 2 blocks/CU

    const int d = blockIdx.y * gridDim.x + blockIdx.x;
    int bx, by;
    if (varK) {   // LPT: heavy column-tiles (large keff) first -> CU pairs heavy+light
        bx = (int)gridDim.x - 1 - (d / (int)gridDim.y);
        by = d % (int)gridDim.y;
    } else {      // bijective XCD swizzle (nwg divisible by 8)
        const int nwg = (int)(gridDim.x * gridDim.y);
        const int cpx = nwg >> 3;
        const int swz = (d & 7) * cpx + (d >> 3);
        bx = swz % (int)gridDim.x;
        by = swz / (int)gridDim.x;
    }

    const int tid = (int)threadIdx.x;
    const int lane = tid & 63, wv = tid >> 6;
    const int wm = wv >> 2, wn = wv & 3;          // wave tile: 128(m) x 64(n)
    const int keff = varK ? min(K, (bx + 1) * BN) : K;
    const int nt = keff >> 5;                     // K-tiles of 32; nt >= 8

    const u16* Ab = A + (size_t)by * BM * K;
    const u16* Bb = Bt + (size_t)bx * BN * K;

    // ---- staging: tile = A 16KB + B 16KB = 4 gloads/thread ----
    // dest linear: buf + [A0|B 8192] + chunk*4096 + tid*8   (chunk = row-half)
    // source row = chunk*128 + (tid>>2); k-slot = (tid&3) ^ ((row>>1)&3)
    const int tr = tid >> 2, ts = tid & 3;
    const int ss = ts ^ ((tr >> 1) & 3);
    const u16* aSrc0 = Ab + (size_t)tr * K + ss * 8;
    const u16* aSrc1 = Ab + (size_t)(tr + 128) * K + ss * 8;
    const u16* bSrc0 = Bb + (size_t)tr * K + ss * 8;
    const u16* bSrc1 = Bb + (size_t)(tr + 128) * K + ss * 8;

#define STAGE(tt)                                                               \
    {                                                                           \
        const int db = ((tt) & 1) * BUFE;                                       \
        const size_t so = (size_t)(tt) * BK;                                    \
        GLDS(aSrc0 + so, lds + db + tid * 8);                                   \
        GLDS(aSrc1 + so, lds + db + 4096 + tid * 8);                            \
        GLDS(bSrc0 + so, lds + db + 8192 + tid * 8);                            \
        GLDS(bSrc1 + so, lds + db + 8192 + 4096 + tid * 8);                     \
    }

    // ---- fragment reads (swizzled slot = (lane>>4) ^ ((l15>>1)&3)) ----
    const int l15 = lane & 15;
    const int sw = (lane >> 4) ^ ((l15 >> 1) & 3);
    const int arow = wm * 128 + l15;
    const int brow = wn * 64 + l15;

#define RDAB(db)                                                                \
    {                                                                           \
        _Pragma("unroll")                                                       \
        for (int i = 0; i < 8; ++i)                                             \
            af[i] = *(const short8*)(lds + (db) + (arow + i * 16) * 32 + sw * 8);\
        _Pragma("unroll")                                                       \
        for (int nf = 0; nf < 4; ++nf)                                          \
            bf[nf] = *(const short8*)(lds + (db) + 8192 + (brow + nf * 16) * 32 \
                                      + sw * 8);                                \
    }
#define MFMA32                                                                  \
    {                                                                           \
        __builtin_amdgcn_s_setprio(1);                                          \
        _Pragma("unroll")                                                       \
        for (int i = 0; i < 8; ++i)                                             \
            _Pragma("unroll")                                                   \
            for (int nf = 0; nf < 4; ++nf)                                      \
                acc[i][nf] = __builtin_amdgcn_mfma_f32_16x16x32_bf16(           \
                    af[i], bf[nf], acc[i][nf], 0, 0, 0);                        \
        __builtin_amdgcn_s_setprio(0);                                          \
    }
#define SB __builtin_amdgcn_sched_barrier(0)
#define BAR __builtin_amdgcn_s_barrier()

    f32x4 acc[8][4];
#pragma unroll
    for (int i = 0; i < 8; ++i)
#pragma unroll
        for (int j = 0; j < 4; ++j)
            acc[i][j] = (f32x4){0.f, 0.f, 0.f, 0.f};

    short8 af[8], bf[4];

    // ---- prologue: stage tiles 0,1; vmcnt(4) = tile0 landed (tile1 in
    //      flight); barrier publishes ----
    STAGE(0); STAGE(1);
    SB; asm volatile("s_waitcnt vmcnt(4)"); SB;
    BAR; SB;

    // Ledger: entry of body T (post BAR2 of T-1): buf(T&1) holds tile T
    // (forced by T-1's vmcnt, published by BAR2); buf((T+1)&1) receiving T+1.
    //   reads(T) -> MFMA (compiler counted-lgkm waits; SB pins cluster)
    //   BAR1: all waves' reads retired -> stage(T+2) into buf(T&1) WAR-safe
    //   vmcnt(4): T+1's 4 gloads retired (only T+2's 4 newer); tail vmcnt(0)
    //   BAR2: T+1 landing published chip-wide.
    for (int T = 0; T < nt; ++T) {
        const int db = (T & 1) * BUFE;
        RDAB(db);
        MFMA32;
        if (T + 1 < nt) {
            SB; BAR;                       // BAR1
            if (T + 2 < nt) STAGE(T + 2);
            if (T + 2 < nt) { SB; asm volatile("s_waitcnt vmcnt(4)"); SB; }
            else            { SB; asm volatile("s_waitcnt vmcnt(0)"); SB; }
            BAR; SB;                       // BAR2
        }
    }

    // ---- epilogue: bias + relu + bf16 store (16x16 C/D layout, verified) ----
    const int rbase = by * BM + wm * 128 + (lane >> 4) * 4;
    const int cbase = bx * BN + wn * 64 + l15;
#pragma unroll
    for (int nf = 0; nf < 4; ++nf) {
        const int gc = cbase + nf * 16;
        const float bv = bias[gc];
#pragma unroll
        for (int mf = 0; mf < 8; ++mf) {
#pragma unroll
            for (int r = 0; r < 4; ++r) {
                int gr = rbase + mf * 16 + r;
                float h = acc[mf][nf][r] + bv;
                h = fmaxf(h, 0.0f);
                C[(size_t)gr * N + gc] = f2bf(h);
            }
        }
    }
#undef STAGE
#undef RDAB
#undef MFMA32
#undef SB
#undef BAR
}

// ---------------- final matvec: out[m] = act[m,:] . col + b3[K-1] ----------------
__global__ __launch_bounds__(256) void k_matvec(const u16* __restrict__ act,
                                                const float* __restrict__ col,
                                                const float* __restrict__ b3,
                                                float* __restrict__ out, int K) {
    const int m = blockIdx.x, t = (int)threadIdx.x;
    const u16* row = act + (size_t)m * K;
    float acc = 0.f;
#pragma unroll
    for (int j = 0; j < 2; ++j) {
        int base = t * 16 + j * 8;
        short8 v = *(const short8*)(row + base);
#pragma unroll
        for (int u = 0; u < 8; ++u)
            acc += bf2f((u16)v[u]) * col[base + u];
    }
#pragma unroll
    for (int off = 32; off > 0; off >>= 1)
        acc += __shfl_down(acc, off);
    __shared__ float red[4];
    if ((t & 63) == 0) red[t >> 6] = acc;
    __syncthreads();
    if (t == 0) out[m] = red[0] + red[1] + red[2] + red[3] + b3[K - 1];
}

extern "C" void kernel_launch(void* const* d_in, const int* in_sizes, int n_in,
                              void* d_out, int out_size, void* d_ws, size_t ws_size,
                              hipStream_t stream) {
    const float* X  = (const float*)d_in[0];
    const float* W0 = (const float*)d_in[1];
    const float* b0 = (const float*)d_in[2];
    const float* W1 = (const float*)d_in[3];
    const float* b1 = (const float*)d_in[4];
    const float* W2 = (const float*)d_in[5];
    const float* b2 = (const float*)d_in[6];
    const float* W3 = (const float*)d_in[7];
    const float* b3 = (const float*)d_in[8];
    float* out = (float*)d_out;

    const int M = 8192, K0 = 1024, H = 4096;

    char* ws = (char*)d_ws;
    u16* Wt    = (u16*)(ws);                               // 33.5 MB (reused)
    u16* actA  = (u16*)(ws + 33554432);                    // 67.1 MB
    u16* actB  = (u16*)(ws + 33554432 + 67108864);         // 67.1 MB
    u16* Xb    = actB;                                     // alias: dead before actB written
    float* col = (float*)(ws + 33554432 + 2 * 67108864);   // 16 KB

    // 1. X -> bf16
    k_cvt<<<dim3((M * K0) / 1024), 256, 0, stream>>>(X, Xb, (long)M * K0);
    // 2. W0^T (no mask)
    k_transpose<<<dim3(H / 32, K0 / 32), dim3(32, 8), 0, stream>>>(W0, Wt, K0, H, 0);
    // 3. h0 = relu(X @ W0 + b0)
    k_gemm<<<dim3(H / BN, M / BM), 512, 0, stream>>>(Xb, Wt, b0, actA, M, H, K0, 0);
    // 4. W1^T masked
    k_transpose<<<dim3(H / 32, H / 32), dim3(32, 8), 0, stream>>>(W1, Wt, H, H, 1);
    // 5. h1 = relu(h0 @ W1eff + b1)   (variable-K per column tile, LPT order)
    k_gemm<<<dim3(H / BN, M / BM), 512, 0, stream>>>(actA, Wt, b1, actB, M, H, H, 1);
    // 6. W2^T masked
    k_transpose<<<dim3(H / 32, H / 32), dim3(32, 8), 0, stream>>>(W2, Wt, H, H, 1);
    // 7. h2 = relu(h1 @ W2eff + b2)
    k_gemm<<<dim3(H / BN, M / BM), 512, 0, stream>>>(actB, Wt, b2, actA, M, H, H, 1);
    // 8. W3 column 4095
    k_extract<<<dim3(H / 256), 256, 0, stream>>>(W3, col, H);
    // 9. out = h2 @ w3col + b3[4095]
    k_matvec<<<dim3(M), 256, 0, stream>>>(actA, col, b3, out, H);
}